// Round 1
// baseline (592.966 us; speedup 1.0000x reference)
//
#include <hip/hip_runtime.h>
#include <math.h>

// Problem constants
#define NB   4096      // graphs
#define MM   64        // points per graph
#define KNN  3
#define FX   59
#define FIN  62        // FX + 3
#define H    128
#define NN   (NB*MM)       // 262144 nodes
#define NE   (NN*KNN)      // 786432 edges
#define C1   256
#define EPSB 1e-5f

__device__ __forceinline__ float wave_red(float v) {
#pragma unroll
    for (int m = 32; m >= 1; m >>= 1) v += __shfl_xor(v, m, 64);
    return v;
}

// ---------------------------------------------------------------------------
// K1: per-graph kNN + edge MLP (62->128) + ReLU + stats over edges + max-agg
// grid = 4096 blocks (one per graph), 256 threads (lane=node, wave=32-ch group)
// ---------------------------------------------------------------------------
__global__ __launch_bounds__(256) void k_knn_mlp1(
    const float* __restrict__ x, const float* __restrict__ pos,
    const float* __restrict__ W1, const float* __restrict__ b1,
    float* __restrict__ h1max, float* __restrict__ p1s, float* __restrict__ p1q)
{
    __shared__ float pos_s[MM * 3];
    __shared__ float x_s[MM * 61];                    // stride 61 (odd) to dodge bank conflicts
    __shared__ __align__(16) float w1_s[FIN * H];
    __shared__ float b1_s[H];
    __shared__ int   nbr_s[MM * KNN];

    const int blk = blockIdx.x;
    const int tid = threadIdx.x;

    for (int t = tid; t < MM * 3; t += 256) pos_s[t] = pos[blk * (MM * 3) + t];
    for (int t = tid; t < MM * FX; t += 256) {
        int i = t / FX, f = t - i * FX;
        x_s[i * 61 + f] = x[blk * (MM * FX) + t];
    }
    for (int t = tid; t < FIN * H; t += 256) w1_s[t] = W1[t];
    if (tid < H) b1_s[tid] = b1[tid];
    __syncthreads();

    // kNN (threads 0..63, one node each). Strict < keeps earlier index on ties
    // (matches jax top_k stability); self excluded.
    if (tid < MM) {
        const float px = pos_s[tid * 3 + 0];
        const float py = pos_s[tid * 3 + 1];
        const float pz = pos_s[tid * 3 + 2];
        float d0 = 1e30f, d1 = 1e30f, d2 = 1e30f;
        int   i0 = 0, i1 = 0, i2 = 0;
        for (int j = 0; j < MM; ++j) {
            if (j == tid) continue;
            float dx = pos_s[j * 3 + 0] - px;
            float dy = pos_s[j * 3 + 1] - py;
            float dz = pos_s[j * 3 + 2] - pz;
            float d = dx * dx + dy * dy + dz * dz;
            if (d < d2) {
                if (d < d1) {
                    d2 = d1; i2 = i1;
                    if (d < d0) { d1 = d0; i1 = i0; d0 = d; i0 = j; }
                    else        { d1 = d;  i1 = j; }
                } else { d2 = d; i2 = j; }
            }
        }
        nbr_s[tid * 3 + 0] = i0;
        nbr_s[tid * 3 + 1] = i1;
        nbr_s[tid * 3 + 2] = i2;
    }
    __syncthreads();

    const int i  = tid & 63;     // node within graph (lane)
    const int cg = tid >> 6;     // channel group (wave index)
    const int j0 = nbr_s[i * 3 + 0];
    const int j1 = nbr_s[i * 3 + 1];
    const int j2 = nbr_s[i * 3 + 2];
    float rel[3][3];
    {
        const float px = pos_s[i * 3 + 0], py = pos_s[i * 3 + 1], pz = pos_s[i * 3 + 2];
        const int jj[3] = { j0, j1, j2 };
#pragma unroll
        for (int k = 0; k < 3; ++k) {
            rel[k][0] = pos_s[jj[k] * 3 + 0] - px;
            rel[k][1] = pos_s[jj[k] * 3 + 1] - py;
            rel[k][2] = pos_s[jj[k] * 3 + 2] - pz;
        }
    }
    const int node = blk * MM + i;

#pragma unroll
    for (int hh = 0; hh < 2; ++hh) {
        const int cb = cg * 32 + hh * 16;
        float acc0[16], acc1[16], acc2[16];
#pragma unroll
        for (int c = 0; c < 16; ++c) {
            float bv = b1_s[cb + c];
            acc0[c] = bv; acc1[c] = bv; acc2[c] = bv;
        }
        for (int f = 0; f < FX; ++f) {
            float4 wa = *(const float4*)&w1_s[f * H + cb + 0];
            float4 wb = *(const float4*)&w1_s[f * H + cb + 4];
            float4 wc = *(const float4*)&w1_s[f * H + cb + 8];
            float4 wd = *(const float4*)&w1_s[f * H + cb + 12];
            float w[16] = { wa.x, wa.y, wa.z, wa.w, wb.x, wb.y, wb.z, wb.w,
                            wc.x, wc.y, wc.z, wc.w, wd.x, wd.y, wd.z, wd.w };
            float m0 = x_s[j0 * 61 + f];
            float m1 = x_s[j1 * 61 + f];
            float m2 = x_s[j2 * 61 + f];
#pragma unroll
            for (int c = 0; c < 16; ++c) {
                acc0[c] += m0 * w[c];
                acc1[c] += m1 * w[c];
                acc2[c] += m2 * w[c];
            }
        }
#pragma unroll
        for (int f = FX; f < FIN; ++f) {
            float4 wa = *(const float4*)&w1_s[f * H + cb + 0];
            float4 wb = *(const float4*)&w1_s[f * H + cb + 4];
            float4 wc = *(const float4*)&w1_s[f * H + cb + 8];
            float4 wd = *(const float4*)&w1_s[f * H + cb + 12];
            float w[16] = { wa.x, wa.y, wa.z, wa.w, wb.x, wb.y, wb.z, wb.w,
                            wc.x, wc.y, wc.z, wc.w, wd.x, wd.y, wd.z, wd.w };
            float m0 = rel[0][f - FX];
            float m1 = rel[1][f - FX];
            float m2 = rel[2][f - FX];
#pragma unroll
            for (int c = 0; c < 16; ++c) {
                acc0[c] += m0 * w[c];
                acc1[c] += m1 * w[c];
                acc2[c] += m2 * w[c];
            }
        }
        float sv[16], qv[16], mx[16];
#pragma unroll
        for (int c = 0; c < 16; ++c) {
            float h0 = fmaxf(acc0[c], 0.f);
            float h1 = fmaxf(acc1[c], 0.f);
            float h2 = fmaxf(acc2[c], 0.f);
            mx[c] = fmaxf(fmaxf(h0, h1), h2);
            sv[c] = h0 + h1 + h2;
            qv[c] = h0 * h0 + h1 * h1 + h2 * h2;
        }
        // raw (pre-BN) max written; BN1 applied in next layer (a1 > 0)
        *(float4*)&h1max[node * H + cb + 0]  = make_float4(mx[0],  mx[1],  mx[2],  mx[3]);
        *(float4*)&h1max[node * H + cb + 4]  = make_float4(mx[4],  mx[5],  mx[6],  mx[7]);
        *(float4*)&h1max[node * H + cb + 8]  = make_float4(mx[8],  mx[9],  mx[10], mx[11]);
        *(float4*)&h1max[node * H + cb + 12] = make_float4(mx[12], mx[13], mx[14], mx[15]);
        // per-block stats over this block's 192 edges (wave owns its channels)
#pragma unroll
        for (int c = 0; c < 16; ++c) {
            float rs = wave_red(sv[c]);
            float rq = wave_red(qv[c]);
            if (i == 0) {
                p1s[(cb + c) * NB + blk] = rs;
                p1q[(cb + c) * NB + blk] = rq;
            }
        }
    }
}

// ---------------------------------------------------------------------------
// k_stats: per-channel reduce of per-block partials -> BN affine coeffs
// grid = C blocks; affine[c] = g*rsqrt(var+eps), affine[C+c] = be - mu*that
// ---------------------------------------------------------------------------
__global__ __launch_bounds__(256) void k_stats(
    const float* __restrict__ ps, const float* __restrict__ pq, int P,
    float invCnt, const float* __restrict__ g, const float* __restrict__ be,
    float* __restrict__ affine, int C)
{
    const int c = blockIdx.x, tid = threadIdx.x;
    float s = 0.f, q = 0.f;
    for (int p = tid; p < P; p += 256) { s += ps[c * P + p]; q += pq[c * P + p]; }
    s = wave_red(s); q = wave_red(q);
    __shared__ float rs_s[4], rq_s[4];
    if ((tid & 63) == 0) { rs_s[tid >> 6] = s; rq_s[tid >> 6] = q; }
    __syncthreads();
    if (tid == 0) {
        float S = rs_s[0] + rs_s[1] + rs_s[2] + rs_s[3];
        float Q = rq_s[0] + rq_s[1] + rq_s[2] + rq_s[3];
        float mu  = S * invCnt;
        float var = Q * invCnt - mu * mu;
        float rsg = rsqrtf(var + EPSB);
        float a   = g[c] * rsg;
        affine[c]     = a;
        affine[C + c] = be[c] - mu * a;
    }
}

// ---------------------------------------------------------------------------
// K3: node MLP (BN1(h1max) -> 128->128 -> ReLU), per-graph sums + stats.
// h2 never materialized (BN2 commutes with mean-pool).
// ---------------------------------------------------------------------------
__global__ __launch_bounds__(256) void k_mlp2(
    const float* __restrict__ h1max, const float* __restrict__ affine1,
    const float* __restrict__ W2, const float* __restrict__ b2,
    float* __restrict__ graphsum, float* __restrict__ p2s, float* __restrict__ p2q)
{
    __shared__ float u_s[MM * 129];   // stride 129: conflict-free column reads
    const int blk = blockIdx.x, tid = threadIdx.x;
    for (int t = tid; t < MM * H; t += 256) {
        int f = t & 127;
        u_s[(t >> 7) * 129 + f] = affine1[f] * h1max[blk * (MM * H) + t] + affine1[H + f];
    }
    __syncthreads();
    const int i  = tid & 63;
    const int cg = __builtin_amdgcn_readfirstlane(tid >> 6);   // wave-uniform -> scalar W2 loads
#pragma unroll
    for (int hh = 0; hh < 2; ++hh) {
        const int cb = cg * 32 + hh * 16;
        float acc[16];
#pragma unroll
        for (int c = 0; c < 16; ++c) acc[c] = b2[cb + c];
        for (int f = 0; f < H; ++f) {
            float uv = u_s[i * 129 + f];
            float4 wa = *(const float4*)&W2[f * H + cb + 0];
            float4 wb = *(const float4*)&W2[f * H + cb + 4];
            float4 wc = *(const float4*)&W2[f * H + cb + 8];
            float4 wd = *(const float4*)&W2[f * H + cb + 12];
            float w[16] = { wa.x, wa.y, wa.z, wa.w, wb.x, wb.y, wb.z, wb.w,
                            wc.x, wc.y, wc.z, wc.w, wd.x, wd.y, wd.z, wd.w };
#pragma unroll
            for (int c = 0; c < 16; ++c) acc[c] += uv * w[c];
        }
#pragma unroll
        for (int c = 0; c < 16; ++c) {
            float y  = fmaxf(acc[c], 0.f);
            float rs = wave_red(y);
            float rq = wave_red(y * y);
            if (i == 0) {
                graphsum[blk * H + cb + c]  = rs;   // per-graph sum (block == graph)
                p2s[(cb + c) * NB + blk] = rs;      // doubles as global-sum partial
                p2q[(cb + c) * NB + blk] = rq;
            }
        }
    }
}

// ---------------------------------------------------------------------------
// K5a: pooled = BN2(graphsum/64); c1 = ReLU(pooled @ Wc1 + bc1); stats over B.
// 256 blocks x 256 threads; block = 16 graphs, thread = one of 256 channels.
// ---------------------------------------------------------------------------
__global__ __launch_bounds__(256) void k_cls1(
    const float* __restrict__ graphsum, const float* __restrict__ affine2,
    const float* __restrict__ Wc1, const float* __restrict__ bc1,
    float* __restrict__ c1raw, float* __restrict__ p3s, float* __restrict__ p3q)
{
    __shared__ float pooled_s[16 * H];
    const int blk = blockIdx.x, tid = threadIdx.x;
    const int g0 = blk * 16;
    for (int t = tid; t < 16 * H; t += 256) {
        int f = t & 127;
        pooled_s[t] = affine2[f] * (graphsum[g0 * H + t] * (1.f / 64.f)) + affine2[H + f];
    }
    __syncthreads();
    const int c = tid;
    float acc[16];
    const float bias = bc1[c];
#pragma unroll
    for (int gi = 0; gi < 16; ++gi) acc[gi] = bias;
    for (int f = 0; f < H; ++f) {
        float w = Wc1[f * C1 + c];
#pragma unroll
        for (int gi = 0; gi < 16; ++gi) acc[gi] += pooled_s[gi * H + f] * w;
    }
    float s = 0.f, q = 0.f;
#pragma unroll
    for (int gi = 0; gi < 16; ++gi) {
        float h = fmaxf(acc[gi], 0.f);
        c1raw[(g0 + gi) * C1 + c] = h;
        s += h; q += h * h;
    }
    p3s[c * 256 + blk] = s;
    p3q[c * 256 + blk] = q;
}

// ---------------------------------------------------------------------------
// K5c: z = ReLU(BN(c1) @ Wc2 + bc2) per graph; partial stats of z over B.
// ---------------------------------------------------------------------------
__global__ __launch_bounds__(256) void k_cls2(
    const float* __restrict__ c1raw, const float* __restrict__ affine3,
    const float* __restrict__ Wc2, const float* __restrict__ bc2,
    float* __restrict__ z, float* __restrict__ pz, float* __restrict__ pzq)
{
    __shared__ float a_s[C1], c_s[C1], w_s[C1];
    const int blk = blockIdx.x, tid = threadIdx.x;
    a_s[tid] = affine3[tid];
    c_s[tid] = affine3[C1 + tid];
    w_s[tid] = Wc2[tid];
    __syncthreads();
    const int g = blk * 256 + tid;
    float acc = bc2[0];
    for (int f = 0; f < C1; f += 4) {
        float4 cv = *(const float4*)&c1raw[g * C1 + f];
        acc += (a_s[f + 0] * cv.x + c_s[f + 0]) * w_s[f + 0];
        acc += (a_s[f + 1] * cv.y + c_s[f + 1]) * w_s[f + 1];
        acc += (a_s[f + 2] * cv.z + c_s[f + 2]) * w_s[f + 2];
        acc += (a_s[f + 3] * cv.w + c_s[f + 3]) * w_s[f + 3];
    }
    float zz = fmaxf(acc, 0.f);
    z[g] = zz;
    float s = wave_red(zz);
    float q = wave_red(zz * zz);
    __shared__ float rs_s[4], rq_s[4];
    if ((tid & 63) == 0) { rs_s[tid >> 6] = s; rq_s[tid >> 6] = q; }
    __syncthreads();
    if (tid == 0) {
        pz[blk]  = rs_s[0] + rs_s[1] + rs_s[2] + rs_s[3];
        pzq[blk] = rq_s[0] + rq_s[1] + rq_s[2] + rq_s[3];
    }
}

// ---------------------------------------------------------------------------
// K5d: final BN over the 4096 z values + sigmoid -> out
// ---------------------------------------------------------------------------
__global__ __launch_bounds__(256) void k_final(
    const float* __restrict__ z, const float* __restrict__ pz,
    const float* __restrict__ pzq, const float* __restrict__ gc2,
    const float* __restrict__ bec2, float* __restrict__ out)
{
    __shared__ float ab[2];
    if (threadIdx.x == 0) {
        float S = 0.f, Q = 0.f;
        for (int p = 0; p < 16; ++p) { S += pz[p]; Q += pzq[p]; }
        float mu  = S * (1.f / 4096.f);
        float var = Q * (1.f / 4096.f) - mu * mu;
        float a   = gc2[0] * rsqrtf(var + EPSB);
        ab[0] = a;
        ab[1] = bec2[0] - mu * a;
    }
    __syncthreads();
    float a = ab[0], cb = ab[1];
    for (int g = threadIdx.x; g < NB; g += 256) {
        float v = a * z[g] + cb;
        out[g] = 1.f / (1.f + expf(-v));
    }
}

extern "C" void kernel_launch(void* const* d_in, const int* in_sizes, int n_in,
                              void* d_out, int out_size, void* d_ws, size_t ws_size,
                              hipStream_t stream)
{
    const float* x    = (const float*)d_in[0];
    const float* pos  = (const float*)d_in[1];
    // d_in[2] = batch (int32) — graphs are contiguous 64-node chunks; unused
    const float* W1   = (const float*)d_in[3];
    const float* b1   = (const float*)d_in[4];
    const float* g1   = (const float*)d_in[5];
    const float* be1  = (const float*)d_in[6];
    const float* W2   = (const float*)d_in[7];
    const float* b2   = (const float*)d_in[8];
    const float* g2   = (const float*)d_in[9];
    const float* be2  = (const float*)d_in[10];
    const float* Wc1  = (const float*)d_in[11];
    const float* bc1  = (const float*)d_in[12];
    const float* gc1  = (const float*)d_in[13];
    const float* bec1 = (const float*)d_in[14];
    const float* Wc2  = (const float*)d_in[15];
    const float* bc2  = (const float*)d_in[16];
    const float* gc2  = (const float*)d_in[17];
    const float* bec2 = (const float*)d_in[18];
    float* out = (float*)d_out;

    float* ws = (float*)d_ws;
    size_t off = 0;
    auto alloc = [&](size_t n) { float* p = ws + off; off += n; return p; };
    float* h1max   = alloc((size_t)NN * H);   // 134 MB
    float* p1s     = alloc((size_t)H * NB);
    float* p1q     = alloc((size_t)H * NB);
    float* affine1 = alloc(2 * H);
    float* graphsum= alloc((size_t)NB * H);
    float* p2s     = alloc((size_t)H * NB);
    float* p2q     = alloc((size_t)H * NB);
    float* affine2 = alloc(2 * H);
    float* c1raw   = alloc((size_t)NB * C1);
    float* p3s     = alloc((size_t)C1 * 256);
    float* p3q     = alloc((size_t)C1 * 256);
    float* affine3 = alloc(2 * C1);
    float* zbuf    = alloc(NB);
    float* pz      = alloc(16);
    float* pzq     = alloc(16);

    k_knn_mlp1<<<dim3(NB), dim3(256), 0, stream>>>(x, pos, W1, b1, h1max, p1s, p1q);
    k_stats<<<dim3(H), dim3(256), 0, stream>>>(p1s, p1q, NB, 1.f / (float)NE, g1, be1, affine1, H);
    k_mlp2<<<dim3(NB), dim3(256), 0, stream>>>(h1max, affine1, W2, b2, graphsum, p2s, p2q);
    k_stats<<<dim3(H), dim3(256), 0, stream>>>(p2s, p2q, NB, 1.f / (float)NN, g2, be2, affine2, H);
    k_cls1<<<dim3(256), dim3(256), 0, stream>>>(graphsum, affine2, Wc1, bc1, c1raw, p3s, p3q);
    k_stats<<<dim3(C1), dim3(256), 0, stream>>>(p3s, p3q, 256, 1.f / (float)NB, gc1, bec1, affine3, C1);
    k_cls2<<<dim3(16), dim3(256), 0, stream>>>(c1raw, affine3, Wc2, bc2, zbuf, pz, pzq);
    k_final<<<dim3(1), dim3(256), 0, stream>>>(zbuf, pz, pzq, gc2, bec2, out);
}

// Round 2
// 362.140 us; speedup vs baseline: 1.6374x; 1.6374x over previous
//
#include <hip/hip_runtime.h>
#include <math.h>

// Problem constants
#define NB   4096      // graphs
#define MM   64        // points per graph
#define KNN  3
#define FX   59
#define H    128
#define NN   (NB*MM)       // 262144 nodes
#define NE   (NN*KNN)      // 786432 edges
#define C1   256
#define EPSB 1e-5f

typedef __attribute__((ext_vector_type(8))) short short8;   // 8 bf16 (4 VGPRs)
typedef __attribute__((ext_vector_type(4))) float f32x4;

__device__ __forceinline__ float wave_red(float v) {
#pragma unroll
    for (int m = 32; m >= 1; m >>= 1) v += __shfl_xor(v, m, 64);
    return v;
}

__device__ __forceinline__ unsigned short f2bf(float f) {
    union { float f; unsigned u; } v; v.f = f;
    unsigned r = v.u + 0x7fffu + ((v.u >> 16) & 1u);   // round-to-nearest-even
    return (unsigned short)(r >> 16);
}

// ---------------------------------------------------------------------------
// prep1: W1t[n][k] = bf16(W1[k][n]), k padded 62->64 with zeros. grid=128,blk=64
// ---------------------------------------------------------------------------
__global__ __launch_bounds__(64) void k_prep1(
    const float* __restrict__ W1, unsigned short* __restrict__ W1t)
{
    const int n = blockIdx.x, k = threadIdx.x;
    W1t[n * 64 + k] = (k < 62) ? f2bf(W1[k * H + n]) : (unsigned short)0;
}

// ---------------------------------------------------------------------------
// prep2 (after BN1 stats): W2t[n][k] = bf16(a1[k]*W2[k][n]);
// b2p[n] = b2[n] + sum_k c1[k]*W2[k][n].  grid=128, blk=128
// ---------------------------------------------------------------------------
__global__ __launch_bounds__(128) void k_prep2(
    const float* __restrict__ W2, const float* __restrict__ affine1,
    const float* __restrict__ b2, unsigned short* __restrict__ W2t,
    float* __restrict__ b2p)
{
    const int n = blockIdx.x, k = threadIdx.x;
    float wv = W2[k * H + n];
    W2t[n * H + k] = f2bf(affine1[k] * wv);
    float contrib = wave_red(affine1[H + k] * wv);
    __shared__ float red2[2];
    if ((k & 63) == 0) red2[k >> 6] = contrib;
    __syncthreads();
    if (k == 0) b2p[n] = b2[n] + red2[0] + red2[1];
}

// ---------------------------------------------------------------------------
// K1: per-graph: u = [x,pos]@W1 via MFMA (64x64 @ 64x128) -> LDS;
// kNN; h_edge = u[j]-w[i]+b1; relu; max-agg -> h1max (bf16); BN1 partials.
// grid = 4096 (graph per block), 256 threads.
// ---------------------------------------------------------------------------
__global__ __launch_bounds__(256) void k_knn_mfma1(
    const float* __restrict__ x, const float* __restrict__ pos,
    const unsigned short* __restrict__ W1t, const float* __restrict__ W1,
    const float* __restrict__ b1,
    unsigned short* __restrict__ h1max, float* __restrict__ p1s,
    float* __restrict__ p1q)
{
    __shared__ float pos_s[MM * 3];
    __shared__ int   nbr_s[MM * 3];
    __shared__ float b1_s[H];
    __shared__ float w1p_s[3 * H];
    __shared__ __align__(16) unsigned short a_s[MM * 72];  // 64x64 bf16, stride 72
    __shared__ __align__(16) float u_s[MM * 129];          // 64x128 f32, stride 129

    const int blk = blockIdx.x, tid = threadIdx.x;
    const float* xg = x + (size_t)blk * MM * FX;
    const float* pg = pos + (size_t)blk * MM * 3;

    for (int t = tid; t < MM * FX; t += 256) a_s[(t / FX) * 72 + t % FX] = f2bf(xg[t]);
    for (int t = tid; t < MM * 3; t += 256) {
        float pv = pg[t];
        pos_s[t] = pv;
        a_s[(t / 3) * 72 + FX + (t % 3)] = f2bf(pv);
    }
    if (tid < 128) a_s[(tid & 63) * 72 + 62 + (tid >> 6)] = 0;  // K-pad
    if (tid < H) b1_s[tid] = b1[tid];
    for (int t = tid; t < 3 * H; t += 256) w1p_s[t] = W1[(FX + t / H) * H + (t % H)];
    __syncthreads();

    // kNN on wave 0 (strict < keeps earlier index on ties, matches top_k)
    if (tid < MM) {
        const float px = pos_s[tid * 3 + 0];
        const float py = pos_s[tid * 3 + 1];
        const float pz = pos_s[tid * 3 + 2];
        float d0 = 1e30f, d1 = 1e30f, d2 = 1e30f;
        int   i0 = 0, i1 = 0, i2 = 0;
        for (int j = 0; j < MM; ++j) {
            if (j == tid) continue;
            float dx = pos_s[j * 3 + 0] - px;
            float dy = pos_s[j * 3 + 1] - py;
            float dz = pos_s[j * 3 + 2] - pz;
            float d = dx * dx + dy * dy + dz * dz;
            if (d < d2) {
                if (d < d1) {
                    d2 = d1; i2 = i1;
                    if (d < d0) { d1 = d0; i1 = i0; d0 = d; i0 = j; }
                    else        { d1 = d;  i1 = j; }
                } else { d2 = d; i2 = j; }
            }
        }
        nbr_s[tid * 3 + 0] = i0;
        nbr_s[tid * 3 + 1] = i1;
        nbr_s[tid * 3 + 2] = i2;
    }

    // MFMA: u(64x128) = A(64x64) @ B(64x128); wave w owns cols [w*32,w*32+32)
    const int lane = tid & 63;
    const int w    = tid >> 6;
    const int wcol = w * 32;
    const int m    = lane & 15;
    const int kg   = lane >> 4;

    short8 bfr[2][2];
#pragma unroll
    for (int ct = 0; ct < 2; ++ct)
#pragma unroll
        for (int kc = 0; kc < 2; ++kc)
            bfr[ct][kc] = *(const short8*)(W1t + (wcol + ct * 16 + m) * 64 + kc * 32 + kg * 8);

    f32x4 acc[4][2];
#pragma unroll
    for (int rt = 0; rt < 4; ++rt)
#pragma unroll
        for (int ct = 0; ct < 2; ++ct) acc[rt][ct] = (f32x4){0.f, 0.f, 0.f, 0.f};

#pragma unroll
    for (int kc = 0; kc < 2; ++kc)
#pragma unroll
        for (int rt = 0; rt < 4; ++rt) {
            short8 a = *(const short8*)(a_s + (rt * 16 + m) * 72 + kc * 32 + kg * 8);
#pragma unroll
            for (int ct = 0; ct < 2; ++ct)
                acc[rt][ct] = __builtin_amdgcn_mfma_f32_16x16x32_bf16(a, bfr[ct][kc], acc[rt][ct], 0, 0, 0);
        }
    // D layout: col = lane&15, row = (lane>>4)*4 + reg  [m89/m91]
#pragma unroll
    for (int rt = 0; rt < 4; ++rt)
#pragma unroll
        for (int ct = 0; ct < 2; ++ct)
#pragma unroll
            for (int r = 0; r < 4; ++r)
                u_s[(rt * 16 + kg * 4 + r) * 129 + wcol + ct * 16 + m] = acc[rt][ct][r];
    __syncthreads();

    // combine: wave = (ch-half, node-half); lane = channel within 64-half
    const int c  = (w & 1) * 64 + lane;
    const int nh = w >> 1;
    const float b1v = b1_s[c];
    const float wp0 = w1p_s[0 * H + c], wp1 = w1p_s[1 * H + c], wp2 = w1p_s[2 * H + c];
    float s_sum = 0.f, s_sq = 0.f;
    unsigned short* hout = h1max + (size_t)blk * MM * H;
    for (int ii = 0; ii < 32; ++ii) {
        int node = nh * 32 + ii;
        int j0 = nbr_s[node * 3 + 0];
        int j1 = nbr_s[node * 3 + 1];
        int j2 = nbr_s[node * 3 + 2];
        float wi = pos_s[node * 3 + 0] * wp0 + pos_s[node * 3 + 1] * wp1
                 + pos_s[node * 3 + 2] * wp2;
        float base = b1v - wi;
        float h0 = fmaxf(u_s[j0 * 129 + c] + base, 0.f);
        float h1 = fmaxf(u_s[j1 * 129 + c] + base, 0.f);
        float h2 = fmaxf(u_s[j2 * 129 + c] + base, 0.f);
        s_sum += h0 + h1 + h2;
        s_sq  += h0 * h0 + h1 * h1 + h2 * h2;
        hout[node * H + c] = f2bf(fmaxf(fmaxf(h0, h1), h2));
    }
    p1s[(size_t)c * (2 * NB) + blk * 2 + nh] = s_sum;
    p1q[(size_t)c * (2 * NB) + blk * 2 + nh] = s_sq;
}

// ---------------------------------------------------------------------------
// k_stats: per-channel reduce of partials -> BN affine (a, c)
// ---------------------------------------------------------------------------
__global__ __launch_bounds__(256) void k_stats(
    const float* __restrict__ ps, const float* __restrict__ pq, int P,
    float invCnt, const float* __restrict__ g, const float* __restrict__ be,
    float* __restrict__ affine, int C)
{
    const int c = blockIdx.x, tid = threadIdx.x;
    float s = 0.f, q = 0.f;
    for (int p = tid; p < P; p += 256) { s += ps[(size_t)c * P + p]; q += pq[(size_t)c * P + p]; }
    s = wave_red(s); q = wave_red(q);
    __shared__ float rs_s[4], rq_s[4];
    if ((tid & 63) == 0) { rs_s[tid >> 6] = s; rq_s[tid >> 6] = q; }
    __syncthreads();
    if (tid == 0) {
        float S = rs_s[0] + rs_s[1] + rs_s[2] + rs_s[3];
        float Q = rq_s[0] + rq_s[1] + rq_s[2] + rq_s[3];
        float mu  = S * invCnt;
        float var = Q * invCnt - mu * mu;
        float a   = g[c] * rsqrtf(var + EPSB);
        affine[c]     = a;
        affine[C + c] = be[c] - mu * a;
    }
}

// ---------------------------------------------------------------------------
// K3: h2 = relu(h1max(bf16) @ W2t + b2p) via MFMA; per-graph col sums + stats.
// grid = 4096 (graph per block), 256 threads; wave owns 32 cols over all 64 rows
// ---------------------------------------------------------------------------
__global__ __launch_bounds__(256) void k_mfma2(
    const unsigned short* __restrict__ h1max, const unsigned short* __restrict__ W2t,
    const float* __restrict__ b2p,
    float* __restrict__ graphsum, float* __restrict__ p2s, float* __restrict__ p2q)
{
    __shared__ __align__(16) unsigned short a_s[MM * 136];  // 64x128 bf16, stride 136
    const int blk = blockIdx.x, tid = threadIdx.x;
    const unsigned short* hg = h1max + (size_t)blk * MM * H;
    for (int t = tid; t < MM * H / 8; t += 256) {
        int row = t >> 4, col8 = (t & 15) * 8;
        *(short8*)(a_s + row * 136 + col8) = *(const short8*)(hg + row * H + col8);
    }
    __syncthreads();

    const int lane = tid & 63, w = tid >> 6, wcol = w * 32;
    const int m = lane & 15, kg = lane >> 4;

    short8 bfr[2][4];
#pragma unroll
    for (int ct = 0; ct < 2; ++ct)
#pragma unroll
        for (int kc = 0; kc < 4; ++kc)
            bfr[ct][kc] = *(const short8*)(W2t + (wcol + ct * 16 + m) * H + kc * 32 + kg * 8);

    f32x4 acc[4][2];
#pragma unroll
    for (int rt = 0; rt < 4; ++rt)
#pragma unroll
        for (int ct = 0; ct < 2; ++ct) acc[rt][ct] = (f32x4){0.f, 0.f, 0.f, 0.f};

#pragma unroll
    for (int kc = 0; kc < 4; ++kc)
#pragma unroll
        for (int rt = 0; rt < 4; ++rt) {
            short8 a = *(const short8*)(a_s + (rt * 16 + m) * 136 + kc * 32 + kg * 8);
#pragma unroll
            for (int ct = 0; ct < 2; ++ct)
                acc[rt][ct] = __builtin_amdgcn_mfma_f32_16x16x32_bf16(a, bfr[ct][kc], acc[rt][ct], 0, 0, 0);
        }

#pragma unroll
    for (int ct = 0; ct < 2; ++ct) {
        float bv = b2p[wcol + ct * 16 + m];
        float s = 0.f, q = 0.f;
#pragma unroll
        for (int rt = 0; rt < 4; ++rt)
#pragma unroll
            for (int r = 0; r < 4; ++r) {
                float v = fmaxf(acc[rt][ct][r] + bv, 0.f);
                s += v; q += v * v;
            }
        s += __shfl_xor(s, 16, 64); q += __shfl_xor(q, 16, 64);
        s += __shfl_xor(s, 32, 64); q += __shfl_xor(q, 32, 64);
        if (lane < 16) {
            int col = wcol + ct * 16 + lane;
            graphsum[(size_t)blk * H + col] = s;
            p2s[(size_t)col * NB + blk] = s;
            p2q[(size_t)col * NB + blk] = q;
        }
    }
}

// ---------------------------------------------------------------------------
// K5a: pooled = BN2(graphsum/64); c1 = ReLU(pooled @ Wc1 + bc1); stats over B.
// ---------------------------------------------------------------------------
__global__ __launch_bounds__(256) void k_cls1(
    const float* __restrict__ graphsum, const float* __restrict__ affine2,
    const float* __restrict__ Wc1, const float* __restrict__ bc1,
    float* __restrict__ c1raw, float* __restrict__ p3s, float* __restrict__ p3q)
{
    __shared__ float pooled_s[16 * H];
    const int blk = blockIdx.x, tid = threadIdx.x;
    const int g0 = blk * 16;
    for (int t = tid; t < 16 * H; t += 256) {
        int f = t & 127;
        pooled_s[t] = affine2[f] * (graphsum[(size_t)g0 * H + t] * (1.f / 64.f)) + affine2[H + f];
    }
    __syncthreads();
    const int c = tid;
    float acc[16];
    const float bias = bc1[c];
#pragma unroll
    for (int gi = 0; gi < 16; ++gi) acc[gi] = bias;
    for (int f = 0; f < H; ++f) {
        float w = Wc1[f * C1 + c];
#pragma unroll
        for (int gi = 0; gi < 16; ++gi) acc[gi] += pooled_s[gi * H + f] * w;
    }
    float s = 0.f, q = 0.f;
#pragma unroll
    for (int gi = 0; gi < 16; ++gi) {
        float h = fmaxf(acc[gi], 0.f);
        c1raw[(size_t)(g0 + gi) * C1 + c] = h;
        s += h; q += h * h;
    }
    p3s[c * 256 + blk] = s;
    p3q[c * 256 + blk] = q;
}

// ---------------------------------------------------------------------------
// K5c: z = ReLU(BN(c1) @ Wc2 + bc2) per graph; partial stats of z.
// ---------------------------------------------------------------------------
__global__ __launch_bounds__(256) void k_cls2(
    const float* __restrict__ c1raw, const float* __restrict__ affine3,
    const float* __restrict__ Wc2, const float* __restrict__ bc2,
    float* __restrict__ z, float* __restrict__ pz, float* __restrict__ pzq)
{
    __shared__ float a_s[C1], c_s[C1], w_s[C1];
    const int blk = blockIdx.x, tid = threadIdx.x;
    a_s[tid] = affine3[tid];
    c_s[tid] = affine3[C1 + tid];
    w_s[tid] = Wc2[tid];
    __syncthreads();
    const int g = blk * 256 + tid;
    float acc = bc2[0];
    for (int f = 0; f < C1; f += 4) {
        float4 cv = *(const float4*)&c1raw[(size_t)g * C1 + f];
        acc += (a_s[f + 0] * cv.x + c_s[f + 0]) * w_s[f + 0];
        acc += (a_s[f + 1] * cv.y + c_s[f + 1]) * w_s[f + 1];
        acc += (a_s[f + 2] * cv.z + c_s[f + 2]) * w_s[f + 2];
        acc += (a_s[f + 3] * cv.w + c_s[f + 3]) * w_s[f + 3];
    }
    float zz = fmaxf(acc, 0.f);
    z[g] = zz;
    float s = wave_red(zz);
    float q = wave_red(zz * zz);
    __shared__ float rs_s[4], rq_s[4];
    if ((tid & 63) == 0) { rs_s[tid >> 6] = s; rq_s[tid >> 6] = q; }
    __syncthreads();
    if (tid == 0) {
        pz[blk]  = rs_s[0] + rs_s[1] + rs_s[2] + rs_s[3];
        pzq[blk] = rq_s[0] + rq_s[1] + rq_s[2] + rq_s[3];
    }
}

// ---------------------------------------------------------------------------
// K5d: final BN over 4096 z + sigmoid -> out
// ---------------------------------------------------------------------------
__global__ __launch_bounds__(256) void k_final(
    const float* __restrict__ z, const float* __restrict__ pz,
    const float* __restrict__ pzq, const float* __restrict__ gc2,
    const float* __restrict__ bec2, float* __restrict__ out)
{
    __shared__ float ab[2];
    if (threadIdx.x == 0) {
        float S = 0.f, Q = 0.f;
        for (int p = 0; p < 16; ++p) { S += pz[p]; Q += pzq[p]; }
        float mu  = S * (1.f / 4096.f);
        float var = Q * (1.f / 4096.f) - mu * mu;
        float a   = gc2[0] * rsqrtf(var + EPSB);
        ab[0] = a;
        ab[1] = bec2[0] - mu * a;
    }
    __syncthreads();
    float a = ab[0], cb = ab[1];
    for (int g = threadIdx.x; g < NB; g += 256) {
        float v = a * z[g] + cb;
        out[g] = 1.f / (1.f + expf(-v));
    }
}

extern "C" void kernel_launch(void* const* d_in, const int* in_sizes, int n_in,
                              void* d_out, int out_size, void* d_ws, size_t ws_size,
                              hipStream_t stream)
{
    const float* x    = (const float*)d_in[0];
    const float* pos  = (const float*)d_in[1];
    // d_in[2] = batch (int32) — graphs are contiguous 64-node chunks; unused
    const float* W1   = (const float*)d_in[3];
    const float* b1   = (const float*)d_in[4];
    const float* g1   = (const float*)d_in[5];
    const float* be1  = (const float*)d_in[6];
    const float* W2   = (const float*)d_in[7];
    const float* b2   = (const float*)d_in[8];
    const float* g2   = (const float*)d_in[9];
    const float* be2  = (const float*)d_in[10];
    const float* Wc1  = (const float*)d_in[11];
    const float* bc1  = (const float*)d_in[12];
    const float* gc1  = (const float*)d_in[13];
    const float* bec1 = (const float*)d_in[14];
    const float* Wc2  = (const float*)d_in[15];
    const float* bc2  = (const float*)d_in[16];
    const float* gc2  = (const float*)d_in[17];
    const float* bec2 = (const float*)d_in[18];
    float* out = (float*)d_out;

    float* ws = (float*)d_ws;
    size_t off = 0;
    auto alloc = [&](size_t n) { float* p = ws + off; off += n; return p; };
    unsigned short* h1max = (unsigned short*)alloc((size_t)NN * H / 2);  // bf16, 67 MB
    unsigned short* W1t   = (unsigned short*)alloc(128 * 64 / 2);
    unsigned short* W2t   = (unsigned short*)alloc(128 * 128 / 2);
    float* b2p     = alloc(H);
    float* p1s     = alloc((size_t)H * 2 * NB);
    float* p1q     = alloc((size_t)H * 2 * NB);
    float* affine1 = alloc(2 * H);
    float* graphsum= alloc((size_t)NB * H);
    float* p2s     = alloc((size_t)H * NB);
    float* p2q     = alloc((size_t)H * NB);
    float* affine2 = alloc(2 * H);
    float* c1raw   = alloc((size_t)NB * C1);
    float* p3s     = alloc((size_t)C1 * 256);
    float* p3q     = alloc((size_t)C1 * 256);
    float* affine3 = alloc(2 * C1);
    float* zbuf    = alloc(NB);
    float* pz      = alloc(16);
    float* pzq     = alloc(16);

    k_prep1<<<dim3(128), dim3(64), 0, stream>>>(W1, W1t);
    k_knn_mfma1<<<dim3(NB), dim3(256), 0, stream>>>(x, pos, W1t, W1, b1, h1max, p1s, p1q);
    k_stats<<<dim3(H), dim3(256), 0, stream>>>(p1s, p1q, 2 * NB, 1.f / (float)NE, g1, be1, affine1, H);
    k_prep2<<<dim3(128), dim3(128), 0, stream>>>(W2, affine1, b2, W2t, b2p);
    k_mfma2<<<dim3(NB), dim3(256), 0, stream>>>(h1max, W2t, b2p, graphsum, p2s, p2q);
    k_stats<<<dim3(H), dim3(256), 0, stream>>>(p2s, p2q, NB, 1.f / (float)NN, g2, be2, affine2, H);
    k_cls1<<<dim3(256), dim3(256), 0, stream>>>(graphsum, affine2, Wc1, bc1, c1raw, p3s, p3q);
    k_stats<<<dim3(C1), dim3(256), 0, stream>>>(p3s, p3q, 256, 1.f / (float)NB, gc1, bec1, affine3, C1);
    k_cls2<<<dim3(16), dim3(256), 0, stream>>>(c1raw, affine3, Wc2, bc2, zbuf, pz, pzq);
    k_final<<<dim3(1), dim3(256), 0, stream>>>(zbuf, pz, pzq, gc2, bec2, out);
}

// Round 3
// 311.127 us; speedup vs baseline: 1.9059x; 1.1640x over previous
//
#include <hip/hip_runtime.h>
#include <math.h>

// Problem constants
#define NB   4096      // graphs
#define MM   64        // points per graph
#define KNN  3
#define FX   59
#define H    128
#define NN   (NB*MM)       // 262144 nodes
#define NE   (NN*KNN)      // 786432 edges
#define C1   256
#define EPSB 1e-5f

typedef __attribute__((ext_vector_type(8))) short short8;   // 8 bf16 (4 VGPRs)
typedef __attribute__((ext_vector_type(4))) float f32x4;

__device__ __forceinline__ float wave_red(float v) {
#pragma unroll
    for (int m = 32; m >= 1; m >>= 1) v += __shfl_xor(v, m, 64);
    return v;
}

__device__ __forceinline__ unsigned short f2bf(float f) {
    union { float f; unsigned u; } v; v.f = f;
    unsigned r = v.u + 0x7fffu + ((v.u >> 16) & 1u);   // round-to-nearest-even
    return (unsigned short)(r >> 16);
}

__device__ __forceinline__ float bf2f(unsigned short h) {
    union { unsigned u; float f; } v; v.u = ((unsigned)h) << 16; return v.f;
}

// ---------------------------------------------------------------------------
// prepx: xpad[node][64] = bf16([x_node | pos_node | 0 0]). grid=NB, blk=256.
// Thread = quarter node row (16 cols).
// ---------------------------------------------------------------------------
__global__ __launch_bounds__(256) void k_prepx(
    const float* __restrict__ x, const float* __restrict__ pos,
    unsigned short* __restrict__ xpad)
{
    const int blk = blockIdx.x, tid = threadIdx.x;
    const float* xg = x + (size_t)blk * MM * FX;
    const float* pg = pos + (size_t)blk * MM * 3;
    unsigned short* op = xpad + (size_t)blk * MM * 64;
    const int node = tid >> 2, c0 = (tid & 3) * 16;
    unsigned short vals[16];
#pragma unroll
    for (int i = 0; i < 16; ++i) {
        int c = c0 + i;
        float v = (c < FX) ? xg[node * FX + c]
                           : ((c < 62) ? pg[node * 3 + (c - FX)] : 0.f);
        vals[i] = f2bf(v);
    }
    *(short8*)(op + node * 64 + c0)     = *(short8*)&vals[0];
    *(short8*)(op + node * 64 + c0 + 8) = *(short8*)&vals[8];
}

// ---------------------------------------------------------------------------
// prep1: W1t[n][k] = bf16(W1[k][n]), k padded 62->64 with zeros. grid=128,blk=64
// ---------------------------------------------------------------------------
__global__ __launch_bounds__(64) void k_prep1(
    const float* __restrict__ W1, unsigned short* __restrict__ W1t)
{
    const int n = blockIdx.x, k = threadIdx.x;
    W1t[n * 64 + k] = (k < 62) ? f2bf(W1[k * H + n]) : (unsigned short)0;
}

// ---------------------------------------------------------------------------
// prep2 (after BN1 stats): W2t[n][k] = bf16(a1[k]*W2[k][n]);
// b2p[n] = b2[n] + sum_k c1[k]*W2[k][n].  grid=128, blk=128
// ---------------------------------------------------------------------------
__global__ __launch_bounds__(128) void k_prep2(
    const float* __restrict__ W2, const float* __restrict__ affine1,
    const float* __restrict__ b2, unsigned short* __restrict__ W2t,
    float* __restrict__ b2p)
{
    const int n = blockIdx.x, k = threadIdx.x;
    float wv = W2[k * H + n];
    W2t[n * H + k] = f2bf(affine1[k] * wv);
    float contrib = wave_red(affine1[H + k] * wv);
    __shared__ float red2[2];
    if ((k & 63) == 0) red2[k >> 6] = contrib;
    __syncthreads();
    if (k == 0) b2p[n] = b2[n] + red2[0] + red2[1];
}

// ---------------------------------------------------------------------------
// K1: per-graph: u = xpad@W1t via MFMA (64x64 @ 64x128) -> LDS (bf16);
// kNN; h_edge = u[j]-w[i]+b1; relu; max-agg -> h1max (bf16); BN1 partials.
// grid = 4096, 256 threads. LDS ~29.7 KB -> 5 blocks/CU.
// ---------------------------------------------------------------------------
__global__ __launch_bounds__(256) void k_knn_mfma1(
    const float* __restrict__ pos, const unsigned short* __restrict__ xpad,
    const unsigned short* __restrict__ W1t, const float* __restrict__ W1,
    const float* __restrict__ b1,
    unsigned short* __restrict__ h1max, float* __restrict__ p1s,
    float* __restrict__ p1q)
{
    __shared__ float pos_s[MM * 3];
    __shared__ int   nbr_s[MM * 3];
    __shared__ float b1_s[H];
    __shared__ float w1p_s[3 * H];
    __shared__ __align__(16) unsigned short a_s[MM * 72];   // 64x64 bf16, stride 72
    __shared__ __align__(16) unsigned short u_s[MM * 132];  // 64x128 bf16, stride 132

    const int blk = blockIdx.x, tid = threadIdx.x;
    const float* pg = pos + (size_t)blk * MM * 3;
    const unsigned short* xp = xpad + (size_t)blk * MM * 64;

    // stage A (vector copies; xpad already bf16, padded, zero-filled k=62..63)
    {
        int r0 = tid >> 3, g0 = (tid & 7) * 8;
        *(short8*)(a_s + r0 * 72 + g0) = *(const short8*)(xp + r0 * 64 + g0);
        int t1 = tid + 256;
        int r1 = t1 >> 3, g1 = (t1 & 7) * 8;
        *(short8*)(a_s + r1 * 72 + g1) = *(const short8*)(xp + r1 * 64 + g1);
    }
    for (int t = tid; t < MM * 3; t += 256) pos_s[t] = pg[t];
    if (tid < H) b1_s[tid] = b1[tid];
    for (int t = tid; t < 3 * H; t += 256) w1p_s[t] = W1[(FX + t / H) * H + (t % H)];
    __syncthreads();

    // kNN on wave 0 (strict < keeps earlier index on ties, matches top_k);
    // waves 1-3 proceed straight to MFMA (no dependence until barrier 2).
    if (tid < MM) {
        const float px = pos_s[tid * 3 + 0];
        const float py = pos_s[tid * 3 + 1];
        const float pz = pos_s[tid * 3 + 2];
        float d0 = 1e30f, d1 = 1e30f, d2 = 1e30f;
        int   i0 = 0, i1 = 0, i2 = 0;
        for (int j = 0; j < MM; ++j) {
            if (j == tid) continue;
            float dx = pos_s[j * 3 + 0] - px;
            float dy = pos_s[j * 3 + 1] - py;
            float dz = pos_s[j * 3 + 2] - pz;
            float d = dx * dx + dy * dy + dz * dz;
            if (d < d2) {
                if (d < d1) {
                    d2 = d1; i2 = i1;
                    if (d < d0) { d1 = d0; i1 = i0; d0 = d; i0 = j; }
                    else        { d1 = d;  i1 = j; }
                } else { d2 = d; i2 = j; }
            }
        }
        nbr_s[tid * 3 + 0] = i0;
        nbr_s[tid * 3 + 1] = i1;
        nbr_s[tid * 3 + 2] = i2;
    }

    // MFMA: u(64x128) = A(64x64) @ B(64x128); wave w owns cols [w*32,w*32+32)
    const int lane = tid & 63;
    const int w    = tid >> 6;
    const int wcol = w * 32;
    const int m    = lane & 15;
    const int kg   = lane >> 4;

    short8 bfr[2][2];
#pragma unroll
    for (int ct = 0; ct < 2; ++ct)
#pragma unroll
        for (int kc = 0; kc < 2; ++kc)
            bfr[ct][kc] = *(const short8*)(W1t + (wcol + ct * 16 + m) * 64 + kc * 32 + kg * 8);

    f32x4 acc[4][2];
#pragma unroll
    for (int rt = 0; rt < 4; ++rt)
#pragma unroll
        for (int ct = 0; ct < 2; ++ct) acc[rt][ct] = (f32x4){0.f, 0.f, 0.f, 0.f};

#pragma unroll
    for (int kc = 0; kc < 2; ++kc)
#pragma unroll
        for (int rt = 0; rt < 4; ++rt) {
            short8 a = *(const short8*)(a_s + (rt * 16 + m) * 72 + kc * 32 + kg * 8);
#pragma unroll
            for (int ct = 0; ct < 2; ++ct)
                acc[rt][ct] = __builtin_amdgcn_mfma_f32_16x16x32_bf16(a, bfr[ct][kc], acc[rt][ct], 0, 0, 0);
        }
    // D layout: col = lane&15, row = (lane>>4)*4 + reg  [m89/m91]; store bf16
#pragma unroll
    for (int rt = 0; rt < 4; ++rt)
#pragma unroll
        for (int ct = 0; ct < 2; ++ct)
#pragma unroll
            for (int r = 0; r < 4; ++r)
                u_s[(rt * 16 + kg * 4 + r) * 132 + wcol + ct * 16 + m] = f2bf(acc[rt][ct][r]);
    __syncthreads();

    // combine: wave = (ch-half, node-half); lane = channel within 64-half
    const int c  = (w & 1) * 64 + lane;
    const int nh = w >> 1;
    const float b1v = b1_s[c];
    const float wp0 = w1p_s[0 * H + c], wp1 = w1p_s[1 * H + c], wp2 = w1p_s[2 * H + c];
    float s_sum = 0.f, s_sq = 0.f;
    unsigned short* hout = h1max + (size_t)blk * MM * H;
    for (int ii = 0; ii < 32; ++ii) {
        int node = nh * 32 + ii;
        int j0 = nbr_s[node * 3 + 0];
        int j1 = nbr_s[node * 3 + 1];
        int j2 = nbr_s[node * 3 + 2];
        float wi = pos_s[node * 3 + 0] * wp0 + pos_s[node * 3 + 1] * wp1
                 + pos_s[node * 3 + 2] * wp2;
        float base = b1v - wi;
        float h0 = fmaxf(bf2f(u_s[j0 * 132 + c]) + base, 0.f);
        float h1 = fmaxf(bf2f(u_s[j1 * 132 + c]) + base, 0.f);
        float h2 = fmaxf(bf2f(u_s[j2 * 132 + c]) + base, 0.f);
        s_sum += h0 + h1 + h2;
        s_sq  += h0 * h0 + h1 * h1 + h2 * h2;
        hout[node * H + c] = f2bf(fmaxf(fmaxf(h0, h1), h2));
    }
    p1s[(size_t)c * (2 * NB) + blk * 2 + nh] = s_sum;
    p1q[(size_t)c * (2 * NB) + blk * 2 + nh] = s_sq;
}

// ---------------------------------------------------------------------------
// k_stats: per-channel reduce of partials -> BN affine (a, c)
// ---------------------------------------------------------------------------
__global__ __launch_bounds__(256) void k_stats(
    const float* __restrict__ ps, const float* __restrict__ pq, int P,
    float invCnt, const float* __restrict__ g, const float* __restrict__ be,
    float* __restrict__ affine, int C)
{
    const int c = blockIdx.x, tid = threadIdx.x;
    float s = 0.f, q = 0.f;
    for (int p = tid; p < P; p += 256) { s += ps[(size_t)c * P + p]; q += pq[(size_t)c * P + p]; }
    s = wave_red(s); q = wave_red(q);
    __shared__ float rs_s[4], rq_s[4];
    if ((tid & 63) == 0) { rs_s[tid >> 6] = s; rq_s[tid >> 6] = q; }
    __syncthreads();
    if (tid == 0) {
        float S = rs_s[0] + rs_s[1] + rs_s[2] + rs_s[3];
        float Q = rq_s[0] + rq_s[1] + rq_s[2] + rq_s[3];
        float mu  = S * invCnt;
        float var = Q * invCnt - mu * mu;
        float a   = g[c] * rsqrtf(var + EPSB);
        affine[c]     = a;
        affine[C + c] = be[c] - mu * a;
    }
}

// ---------------------------------------------------------------------------
// K3: h2 = relu(h1max(bf16) @ W2t + b2p) via MFMA; per-graph col sums + stats.
// grid = 4096, 256 threads; wave owns 32 cols over all 64 rows
// ---------------------------------------------------------------------------
__global__ __launch_bounds__(256) void k_mfma2(
    const unsigned short* __restrict__ h1max, const unsigned short* __restrict__ W2t,
    const float* __restrict__ b2p,
    float* __restrict__ graphsum, float* __restrict__ p2s, float* __restrict__ p2q)
{
    __shared__ __align__(16) unsigned short a_s[MM * 136];  // 64x128 bf16, stride 136
    const int blk = blockIdx.x, tid = threadIdx.x;
    const unsigned short* hg = h1max + (size_t)blk * MM * H;
    for (int t = tid; t < MM * H / 8; t += 256) {
        int row = t >> 4, col8 = (t & 15) * 8;
        *(short8*)(a_s + row * 136 + col8) = *(const short8*)(hg + row * H + col8);
    }
    __syncthreads();

    const int lane = tid & 63, w = tid >> 6, wcol = w * 32;
    const int m = lane & 15, kg = lane >> 4;

    short8 bfr[2][4];
#pragma unroll
    for (int ct = 0; ct < 2; ++ct)
#pragma unroll
        for (int kc = 0; kc < 4; ++kc)
            bfr[ct][kc] = *(const short8*)(W2t + (wcol + ct * 16 + m) * H + kc * 32 + kg * 8);

    f32x4 acc[4][2];
#pragma unroll
    for (int rt = 0; rt < 4; ++rt)
#pragma unroll
        for (int ct = 0; ct < 2; ++ct) acc[rt][ct] = (f32x4){0.f, 0.f, 0.f, 0.f};

#pragma unroll
    for (int kc = 0; kc < 4; ++kc)
#pragma unroll
        for (int rt = 0; rt < 4; ++rt) {
            short8 a = *(const short8*)(a_s + (rt * 16 + m) * 136 + kc * 32 + kg * 8);
#pragma unroll
            for (int ct = 0; ct < 2; ++ct)
                acc[rt][ct] = __builtin_amdgcn_mfma_f32_16x16x32_bf16(a, bfr[ct][kc], acc[rt][ct], 0, 0, 0);
        }

#pragma unroll
    for (int ct = 0; ct < 2; ++ct) {
        float bv = b2p[wcol + ct * 16 + m];
        float s = 0.f, q = 0.f;
#pragma unroll
        for (int rt = 0; rt < 4; ++rt)
#pragma unroll
            for (int r = 0; r < 4; ++r) {
                float v = fmaxf(acc[rt][ct][r] + bv, 0.f);
                s += v; q += v * v;
            }
        s += __shfl_xor(s, 16, 64); q += __shfl_xor(q, 16, 64);
        s += __shfl_xor(s, 32, 64); q += __shfl_xor(q, 32, 64);
        if (lane < 16) {
            int col = wcol + ct * 16 + lane;
            graphsum[(size_t)blk * H + col] = s;
            p2s[(size_t)col * NB + blk] = s;
            p2q[(size_t)col * NB + blk] = q;
        }
    }
}

// ---------------------------------------------------------------------------
// K5a: pooled = BN2(graphsum/64); c1 = ReLU(pooled @ Wc1 + bc1); stats over B.
// ---------------------------------------------------------------------------
__global__ __launch_bounds__(256) void k_cls1(
    const float* __restrict__ graphsum, const float* __restrict__ affine2,
    const float* __restrict__ Wc1, const float* __restrict__ bc1,
    float* __restrict__ c1raw, float* __restrict__ p3s, float* __restrict__ p3q)
{
    __shared__ float pooled_s[16 * H];
    const int blk = blockIdx.x, tid = threadIdx.x;
    const int g0 = blk * 16;
    for (int t = tid; t < 16 * H; t += 256) {
        int f = t & 127;
        pooled_s[t] = affine2[f] * (graphsum[(size_t)g0 * H + t] * (1.f / 64.f)) + affine2[H + f];
    }
    __syncthreads();
    const int c = tid;
    float acc[16];
    const float bias = bc1[c];
#pragma unroll
    for (int gi = 0; gi < 16; ++gi) acc[gi] = bias;
    for (int f = 0; f < H; ++f) {
        float w = Wc1[f * C1 + c];
#pragma unroll
        for (int gi = 0; gi < 16; ++gi) acc[gi] += pooled_s[gi * H + f] * w;
    }
    float s = 0.f, q = 0.f;
#pragma unroll
    for (int gi = 0; gi < 16; ++gi) {
        float h = fmaxf(acc[gi], 0.f);
        c1raw[(size_t)(g0 + gi) * C1 + c] = h;
        s += h; q += h * h;
    }
    p3s[c * 256 + blk] = s;
    p3q[c * 256 + blk] = q;
}

// ---------------------------------------------------------------------------
// K5c: z = ReLU(BN(c1) @ Wc2 + bc2) per graph; partial stats of z.
// ---------------------------------------------------------------------------
__global__ __launch_bounds__(256) void k_cls2(
    const float* __restrict__ c1raw, const float* __restrict__ affine3,
    const float* __restrict__ Wc2, const float* __restrict__ bc2,
    float* __restrict__ z, float* __restrict__ pz, float* __restrict__ pzq)
{
    __shared__ float a_s[C1], c_s[C1], w_s[C1];
    const int blk = blockIdx.x, tid = threadIdx.x;
    a_s[tid] = affine3[tid];
    c_s[tid] = affine3[C1 + tid];
    w_s[tid] = Wc2[tid];
    __syncthreads();
    const int g = blk * 256 + tid;
    float acc = bc2[0];
    for (int f = 0; f < C1; f += 4) {
        float4 cv = *(const float4*)&c1raw[(size_t)g * C1 + f];
        acc += (a_s[f + 0] * cv.x + c_s[f + 0]) * w_s[f + 0];
        acc += (a_s[f + 1] * cv.y + c_s[f + 1]) * w_s[f + 1];
        acc += (a_s[f + 2] * cv.z + c_s[f + 2]) * w_s[f + 2];
        acc += (a_s[f + 3] * cv.w + c_s[f + 3]) * w_s[f + 3];
    }
    float zz = fmaxf(acc, 0.f);
    z[g] = zz;
    float s = wave_red(zz);
    float q = wave_red(zz * zz);
    __shared__ float rs_s[4], rq_s[4];
    if ((tid & 63) == 0) { rs_s[tid >> 6] = s; rq_s[tid >> 6] = q; }
    __syncthreads();
    if (tid == 0) {
        pz[blk]  = rs_s[0] + rs_s[1] + rs_s[2] + rs_s[3];
        pzq[blk] = rq_s[0] + rq_s[1] + rq_s[2] + rq_s[3];
    }
}

// ---------------------------------------------------------------------------
// K5d: final BN over 4096 z + sigmoid -> out
// ---------------------------------------------------------------------------
__global__ __launch_bounds__(256) void k_final(
    const float* __restrict__ z, const float* __restrict__ pz,
    const float* __restrict__ pzq, const float* __restrict__ gc2,
    const float* __restrict__ bec2, float* __restrict__ out)
{
    __shared__ float ab[2];
    if (threadIdx.x == 0) {
        float S = 0.f, Q = 0.f;
        for (int p = 0; p < 16; ++p) { S += pz[p]; Q += pzq[p]; }
        float mu  = S * (1.f / 4096.f);
        float var = Q * (1.f / 4096.f) - mu * mu;
        float a   = gc2[0] * rsqrtf(var + EPSB);
        ab[0] = a;
        ab[1] = bec2[0] - mu * a;
    }
    __syncthreads();
    float a = ab[0], cb = ab[1];
    for (int g = threadIdx.x; g < NB; g += 256) {
        float v = a * z[g] + cb;
        out[g] = 1.f / (1.f + expf(-v));
    }
}

extern "C" void kernel_launch(void* const* d_in, const int* in_sizes, int n_in,
                              void* d_out, int out_size, void* d_ws, size_t ws_size,
                              hipStream_t stream)
{
    const float* x    = (const float*)d_in[0];
    const float* pos  = (const float*)d_in[1];
    // d_in[2] = batch (int32) — graphs are contiguous 64-node chunks; unused
    const float* W1   = (const float*)d_in[3];
    const float* b1   = (const float*)d_in[4];
    const float* g1   = (const float*)d_in[5];
    const float* be1  = (const float*)d_in[6];
    const float* W2   = (const float*)d_in[7];
    const float* b2   = (const float*)d_in[8];
    const float* g2   = (const float*)d_in[9];
    const float* be2  = (const float*)d_in[10];
    const float* Wc1  = (const float*)d_in[11];
    const float* bc1  = (const float*)d_in[12];
    const float* gc1  = (const float*)d_in[13];
    const float* bec1 = (const float*)d_in[14];
    const float* Wc2  = (const float*)d_in[15];
    const float* bc2  = (const float*)d_in[16];
    const float* gc2  = (const float*)d_in[17];
    const float* bec2 = (const float*)d_in[18];
    float* out = (float*)d_out;

    float* ws = (float*)d_ws;
    size_t off = 0;
    auto alloc = [&](size_t n) { float* p = ws + off; off += n; return p; };
    unsigned short* h1max = (unsigned short*)alloc((size_t)NN * H / 2);  // bf16, 67 MB
    unsigned short* xpad  = (unsigned short*)alloc((size_t)NN * 64 / 2); // bf16, 33.5 MB
    unsigned short* W1t   = (unsigned short*)alloc(128 * 64 / 2);
    unsigned short* W2t   = (unsigned short*)alloc(128 * 128 / 2);
    float* b2p     = alloc(H);
    float* p1s     = alloc((size_t)H * 2 * NB);
    float* p1q     = alloc((size_t)H * 2 * NB);
    float* affine1 = alloc(2 * H);
    float* graphsum= alloc((size_t)NB * H);
    float* p2s     = alloc((size_t)H * NB);
    float* p2q     = alloc((size_t)H * NB);
    float* affine2 = alloc(2 * H);
    float* c1raw   = alloc((size_t)NB * C1);
    float* p3s     = alloc((size_t)C1 * 256);
    float* p3q     = alloc((size_t)C1 * 256);
    float* affine3 = alloc(2 * C1);
    float* zbuf    = alloc(NB);
    float* pz      = alloc(16);
    float* pzq     = alloc(16);

    k_prepx<<<dim3(NB), dim3(256), 0, stream>>>(x, pos, xpad);
    k_prep1<<<dim3(128), dim3(64), 0, stream>>>(W1, W1t);
    k_knn_mfma1<<<dim3(NB), dim3(256), 0, stream>>>(pos, xpad, W1t, W1, b1, h1max, p1s, p1q);
    k_stats<<<dim3(H), dim3(256), 0, stream>>>(p1s, p1q, 2 * NB, 1.f / (float)NE, g1, be1, affine1, H);
    k_prep2<<<dim3(128), dim3(128), 0, stream>>>(W2, affine1, b2, W2t, b2p);
    k_mfma2<<<dim3(NB), dim3(256), 0, stream>>>(h1max, W2t, b2p, graphsum, p2s, p2q);
    k_stats<<<dim3(H), dim3(256), 0, stream>>>(p2s, p2q, NB, 1.f / (float)NN, g2, be2, affine2, H);
    k_cls1<<<dim3(256), dim3(256), 0, stream>>>(graphsum, affine2, Wc1, bc1, c1raw, p3s, p3q);
    k_stats<<<dim3(C1), dim3(256), 0, stream>>>(p3s, p3q, 256, 1.f / (float)NB, gc1, bec1, affine3, C1);
    k_cls2<<<dim3(16), dim3(256), 0, stream>>>(c1raw, affine3, Wc2, bc2, zbuf, pz, pzq);
    k_final<<<dim3(1), dim3(256), 0, stream>>>(zbuf, pz, pzq, gc2, bec2, out);
}